// Round 7
// baseline (490.699 us; speedup 1.0000x reference)
//
#include <hip/hip_runtime.h>
#include <hip/hip_fp16.h>
#include <math.h>

#define GHH 224
#define GWW 224
#define HW (GHH*GWW)     // 50176
#define BATCH 8
#define RAD 3
#define DIAM 7
#define NPTS 49
#define QC 32
#define TH 16               // tile rows
#define TW 32               // tile cols (2 per thread in x)
#define QTH (TH + 2*RAD)    // 22
#define QTW (TW + 2*RAD)    // 38
#define QROW 40             // padded LDS row stride (x16B = 640B, ≡0 mod 128 -> rows bank-aligned)
#define QPLANE 882          // plane stride in float4 (882 % 8 == 2 -> staging writes 2-way minimal)
#define QPIX (QTH*QTW)      // 836

typedef _Float16 h2 __attribute__((ext_vector_type(2)));

#if defined(__has_builtin)
#if __has_builtin(__builtin_amdgcn_fdot2)
#define HAS_FDOT2 1
#endif
#endif

__device__ __forceinline__ h2 as_h2(float f) { union { float f; h2 h; } u; u.f = f; return u.h; }

__device__ __forceinline__ float dot2acc(float a, float b, float acc) {
#ifdef HAS_FDOT2
    return __builtin_amdgcn_fdot2(as_h2(a), as_h2(b), acc, false);
#else
    union { float f; __half2 h; } ua, ub; ua.f = a; ub.f = b;
    float2 fa = __half22float2(ua.h), fb = __half22float2(ub.h);
    return acc + fa.x * fb.x + fa.y * fb.y;
#endif
}

__device__ __forceinline__ float dot16(const float4& a, const float4& b, float acc) {
    acc = dot2acc(a.x, b.x, acc);
    acc = dot2acc(a.y, b.y, acc);
    acc = dot2acc(a.z, b.z, acc);
    acc = dot2acc(a.w, b.w, acc);
    return acc;
}

__device__ __forceinline__ int refl(int i) {
    if (i < 0) i = -i;
    if (i >= GHH) i = 2 * GHH - 2 - i;
    return i;
}

__device__ __forceinline__ float gelu_fast(float v) {
    float u = 0.7978845608f * v * (1.f + 0.044715f * v * v);
    float e = __expf(2.f * u);
    float th = 1.f - 2.f / (e + 1.f);
    return 0.5f * v * (1.f + th);
}

// ---------------- linear ----------------
__global__ void linear_kernel(const float* __restrict__ x,
                              const float* __restrict__ W,
                              const float* __restrict__ bias,
                              float* __restrict__ f0) {
    int gwave = (blockIdx.x * blockDim.x + threadIdx.x) >> 6;
    int lane = threadIdx.x & 63;
    if (gwave >= BATCH * 972) return;
    int b = gwave / 972, j = gwave % 972;
    const float* xr = x + b * 1000;
    const float* wr = W + j * 1000;
    float s = 0.f;
    for (int k = lane; k < 1000; k += 64)
        s += xr[k] * wr[k];
    #pragma unroll
    for (int off = 32; off; off >>= 1) s += __shfl_down(s, off, 64);
    if (lane == 0) f0[gwave] = s + bias[j];
}

// ---------------- bicubic 18 -> 224 ----------------
__device__ __forceinline__ float cubicw(float d) {
    d = fabsf(d);
    if (d <= 1.f) return ((1.25f * d - 2.25f) * d) * d + 1.f;
    if (d < 2.f)  return ((-0.75f * d + 3.75f) * d - 6.f) * d + 3.f;
    return 0.f;
}

__global__ void bicubic_kernel(const float* __restrict__ f0, float* __restrict__ hr) {
    int idx = blockIdx.x * blockDim.x + threadIdx.x;
    if (idx >= BATCH * 3 * HW) return;
    int w = idx % GWW;
    int h = (idx / GWW) % GHH;
    int bc = idx / HW;
    const float* src = f0 + bc * 18 * 18;
    float xx = (w + 0.5f) * (18.f / 224.f) - 0.5f;
    float yy = (h + 0.5f) * (18.f / 224.f) - 0.5f;
    float fx0 = floorf(xx), fy0 = floorf(yy);
    int x0 = (int)fx0, y0 = (int)fy0;
    float tx = xx - fx0, ty = yy - fy0;
    float wx[4], wy[4];
    int ix[4], iy[4];
    #pragma unroll
    for (int k = 0; k < 4; k++) {
        wx[k] = cubicw(tx - (float)(k - 1));
        wy[k] = cubicw(ty - (float)(k - 1));
        int a = x0 + (k - 1); ix[k] = min(max(a, 0), 17);
        a = y0 + (k - 1);     iy[k] = min(max(a, 0), 17);
    }
    float acc = 0.f;
    #pragma unroll
    for (int ky = 0; ky < 4; ky++) {
        float rowv = 0.f;
        #pragma unroll
        for (int kx = 0; kx < 4; kx++) rowv += wx[kx] * src[iy[ky] * 18 + ix[kx]];
        acc += wy[ky] * rowv;
    }
    hr[idx] = acc;
}

// ---------------- range_proj -> f16 q; weights via SGPR (uniform global indices) ----------------
__global__ __launch_bounds__(256) void rangeproj_kernel(
    const float* __restrict__ guid,
    const float* __restrict__ w1, const float* __restrict__ b1,
    const float* __restrict__ w2, const float* __restrict__ b2,
    float4* __restrict__ q4) {
    __shared__ __align__(16) float4 sout[256 * 5];
    int tid = threadIdx.x;
    int idx = blockIdx.x * 256 + tid;
    int b = idx / HW, pix = idx % HW;
    float g0 = guid[(b * 3 + 0) * HW + pix];
    float g1 = guid[(b * 3 + 1) * HW + pix];
    float g2 = guid[(b * 3 + 2) * HW + pix];
    float h1[QC];
    #pragma unroll
    for (int k = 0; k < QC; k++) {
        float v = w1[k * 3] * g0 + w1[k * 3 + 1] * g1 + w1[k * 3 + 2] * g2 + b1[k];
        h1[k] = gelu_fast(v);
    }
    float4 packv[4];
    float* packf = (float*)packv;
    #pragma unroll
    for (int k = 0; k < QC; k += 2) {
        float a0 = b2[k], a1 = b2[k + 1];
        #pragma unroll
        for (int c = 0; c < QC; c++) {
            a0 += w2[k * QC + c] * h1[c];
            a1 += w2[(k + 1) * QC + c] * h1[c];
        }
        union { __half2 h; float f; } u;
        u.h = __floats2half2_rn(a0, a1);
        packf[k >> 1] = u.f;
    }
    #pragma unroll
    for (int j = 0; j < 4; j++) sout[tid * 5 + j] = packv[j];
    __syncthreads();
    size_t gbase = (size_t)blockIdx.x * 1024;
    #pragma unroll
    for (int k2 = 0; k2 < 4; k2++) {
        int t = k2 * 256 + tid;
        q4[gbase + t] = sout[(t >> 2) * 5 + (t & 3)];
    }
}

// ---------------- fused JBU, 1x2 pixels per thread, 16x32 tile ----------------
__global__ __launch_bounds__(256, 2) void jbu_kernel(
    const float4* __restrict__ q4,
    const float* __restrict__ hr,
    float* __restrict__ outF,
    const float* __restrict__ temps,
    const float* __restrict__ sigmas,
    int stage)
{
    __shared__ __align__(16) float4 sq[4 * QPLANE];  // 56448 B
    __shared__ __align__(16) float4 sh[QTH * QROW];  // 14080 B (fixed: covers r*QROW+cc up to 877)
    const int tx = threadIdx.x, ty = threadIdx.y;
    const int tid = ty * 16 + tx;
    const int b = blockIdx.z;
    const int h0 = blockIdx.y * TH, w0 = blockIdx.x * TW;

    const bool interior = (h0 >= RAD) && (h0 + TH + RAD <= GHH) &&
                          (w0 >= RAD) && (w0 + TW + RAD <= GWW);

    if (interior) {
        const float4* qb = q4 + ((size_t)(b * HW + (h0 - RAD) * GWW + (w0 - RAD))) * 4;
        for (int i = tid; i < 4 * QPIX; i += 256) {
            int px = i >> 2, c = i & 3;
            int r = px / QTW, cc = px - r * QTW;
            sq[c * QPLANE + r * QROW + cc] = qb[((size_t)r * GWW + cc) * 4 + c];
        }
        const float* hb = hr + (size_t)b * 3 * HW + (size_t)(h0 - RAD) * GWW + (w0 - RAD);
        for (int i = tid; i < QPIX; i += 256) {
            int r = i / QTW, cc = i - r * QTW;
            size_t base = (size_t)r * GWW + cc;
            sh[r * QROW + cc] = make_float4(hb[base], hb[base + HW], hb[base + 2 * HW], 0.f);
        }
    } else {
        for (int i = tid; i < 4 * QPIX; i += 256) {
            int px = i >> 2, c = i & 3;
            int r = px / QTW, cc = px - r * QTW;
            int gh = refl(h0 - RAD + r);
            int gw = refl(w0 - RAD + cc);
            sq[c * QPLANE + r * QROW + cc] = q4[(size_t)(b * HW + gh * GWW + gw) * 4 + c];
        }
        for (int i = tid; i < QPIX; i += 256) {
            int r = i / QTW, cc = i - r * QTW;
            int gh = refl(h0 - RAD + r);
            int gw = refl(w0 - RAD + cc);
            size_t base = (size_t)b * 3 * HW + (size_t)gh * GWW + gw;
            sh[r * QROW + cc] = make_float4(hr[base], hr[base + HW], hr[base + 2 * HW], 0.f);
        }
    }
    __syncthreads();

    const int col0 = 2 * tx;
    const int cbase = (ty + RAD) * QROW + col0 + RAD;

    float s0[NPTS], s1[NPTS];
    #pragma unroll
    for (int p = 0; p < NPTS; p++) { s0[p] = 0.f; s1[p] = 0.f; }

    // score loop: chunk loop NOT unrolled (keeps live regs low); inner fully unrolled
    #pragma unroll 1
    for (int c = 0; c < 4; c++) {
        const float4* pl = &sq[c * QPLANE];
        const float4 ctr0 = pl[cbase];
        const float4 ctr1 = pl[cbase + 1];
        #pragma unroll
        for (int di = 0; di < DIAM; di++) {
            int rb = (ty + di) * QROW + col0;
            #pragma unroll
            for (int dj = 0; dj < 8; dj++) {
                float4 v = pl[rb + dj];
                if (dj < 7) s0[di * 7 + dj]     = dot16(ctr0, v, s0[di * 7 + dj]);
                if (dj > 0) s1[di * 7 + dj - 1] = dot16(ctr1, v, s1[di * 7 + dj - 1]);
            }
        }
    }

    // ---- softmax * spatial, renormalize (both pixels) ----
    float t = __expf(temps[stage]);
    t = fminf(fmaxf(t, 1e-4f), 1e4f);
    float sig = sigmas[stage];
    float inv2s2 = 1.f / (2.f * sig * sig);
    float m0 = -1e30f, m1 = -1e30f;
    #pragma unroll
    for (int p = 0; p < NPTS; p++) {
        s0[p] *= t; s1[p] *= t;
        m0 = fmaxf(m0, s0[p]); m1 = fmaxf(m1, s1[p]);
    }
    float den0 = 0.f, den1 = 0.f;
    #pragma unroll
    for (int p = 0; p < NPTS; p++) {
        s0[p] = __expf(s0[p] - m0); den0 += s0[p];
        s1[p] = __expf(s1[p] - m1); den1 += s1[p];
    }
    float rden0 = 1.f / den0, rden1 = 1.f / den1;
    float ksum0 = 0.f, ksum1 = 0.f;
    #pragma unroll
    for (int p = 0; p < NPTS; p++) {
        int di = p / 7, dj = p % 7;
        float dy = (float)(di - 3) * (1.f / 3.f);
        float dx = (float)(dj - 3) * (1.f / 3.f);
        float spat = __expf(-(dy * dy + dx * dx) * inv2s2);
        s0[p] = s0[p] * rden0 * spat; ksum0 += s0[p];
        s1[p] = s1[p] * rden1 * spat; ksum1 += s1[p];
    }
    float rk0 = 1.f / fmaxf(ksum0, 1e-7f);
    float rk1 = 1.f / fmaxf(ksum1, 1e-7f);

    // ---- adaptive conv from sh (sh untouched since staging barrier) ----
    float o00 = 0.f, o01 = 0.f, o02 = 0.f;
    float o10 = 0.f, o11 = 0.f, o12 = 0.f;
    #pragma unroll
    for (int di = 0; di < DIAM; di++) {
        int rb = (ty + di) * QROW + col0;
        #pragma unroll
        for (int dj = 0; dj < 8; dj++) {
            float4 hv = sh[rb + dj];
            if (dj < 7) {
                float kp = s0[di * 7 + dj] * rk0;
                o00 += kp * hv.x; o01 += kp * hv.y; o02 += kp * hv.z;
            }
            if (dj > 0) {
                float kp = s1[di * 7 + dj - 1] * rk1;
                o10 += kp * hv.x; o11 += kp * hv.y; o12 += kp * hv.z;
            }
        }
    }
    size_t obase = (size_t)b * 3 * HW + (size_t)(h0 + ty) * GWW + (w0 + col0);
    *(float2*)&outF[obase]          = make_float2(o00, o10);
    *(float2*)&outF[obase + HW]     = make_float2(o01, o11);
    *(float2*)&outF[obase + 2 * HW] = make_float2(o02, o12);
}

extern "C" void kernel_launch(void* const* d_in, const int* in_sizes, int n_in,
                              void* d_out, int out_size, void* d_ws, size_t ws_size,
                              hipStream_t stream) {
    const float* x      = (const float*)d_in[0];
    const float* guid   = (const float*)d_in[1];
    const float* lw     = (const float*)d_in[2];
    const float* lb     = (const float*)d_in[3];
    const float* w1s    = (const float*)d_in[4];
    const float* b1s    = (const float*)d_in[5];
    const float* w2s    = (const float*)d_in[6];
    const float* b2s    = (const float*)d_in[7];
    const float* temps  = (const float*)d_in[8];
    const float* sigmas = (const float*)d_in[9];

    char* ws = (char*)d_ws;
    const size_t Q_BYTES  = (size_t)BATCH * HW * QC * sizeof(__half);  // 25,690,112
    const size_t F_BYTES  = (size_t)BATCH * 3 * HW * sizeof(float);    //  4,816,896
    float4* q4 = (float4*)ws;
    float* hrA = (float*)(ws + Q_BYTES);
    float* hrB = (float*)(ws + Q_BYTES + F_BYTES);
    float* f0  = (float*)(ws + Q_BYTES + 2 * F_BYTES);

    linear_kernel<<<1944, 256, 0, stream>>>(x, lw, lb, f0);
    bicubic_kernel<<<(BATCH * 3 * HW + 255) / 256, 256, 0, stream>>>(f0, hrA);

    dim3 jgrid(GWW / TW, GHH / TH, BATCH), jblock(16, 16);
    const float* hins[4]  = { hrA, hrB, hrA, hrB };
    float*       fouts[4] = { hrB, hrA, hrB, (float*)d_out };
    for (int s = 0; s < 4; s++) {
        rangeproj_kernel<<<(BATCH * HW) / 256, 256, 0, stream>>>(
            guid, w1s + s * 96, b1s + s * 32, w2s + s * 1024, b2s + s * 32, q4);
        jbu_kernel<<<jgrid, jblock, 0, stream>>>(
            q4, hins[s], fouts[s], temps, sigmas, s);
    }
}

// Round 8
// 333.416 us; speedup vs baseline: 1.4717x; 1.4717x over previous
//
#include <hip/hip_runtime.h>
#include <hip/hip_fp16.h>
#include <math.h>

#define GHH 224
#define GWW 224
#define HW (GHH*GWW)     // 50176
#define BATCH 8
#define RAD 3
#define DIAM 7
#define NPTS 49
#define QC 32
#define TILE 16
#define TP (TILE + 2*RAD)   // 22
#define TPIX (TP*TP)        // 484
#define CS 485              // chunk-plane stride in float4

typedef _Float16 h2 __attribute__((ext_vector_type(2)));
typedef _Float16 v8h __attribute__((ext_vector_type(8)));
typedef float v4f __attribute__((ext_vector_type(4)));

#if defined(__has_builtin)
#if __has_builtin(__builtin_amdgcn_fdot2)
#define HAS_FDOT2 1
#endif
#endif

__device__ __forceinline__ h2 as_h2(float f) { union { float f; h2 h; } u; u.f = f; return u.h; }

__device__ __forceinline__ float dot2acc(float a, float b, float acc) {
#ifdef HAS_FDOT2
    return __builtin_amdgcn_fdot2(as_h2(a), as_h2(b), acc, false);
#else
    union { float f; __half2 h; } ua, ub; ua.f = a; ub.f = b;
    float2 fa = __half22float2(ua.h), fb = __half22float2(ub.h);
    return acc + fa.x * fb.x + fa.y * fb.y;
#endif
}

__device__ __forceinline__ float dot16(const float4& a, const float4& b, float acc) {
    acc = dot2acc(a.x, b.x, acc);
    acc = dot2acc(a.y, b.y, acc);
    acc = dot2acc(a.z, b.z, acc);
    acc = dot2acc(a.w, b.w, acc);
    return acc;
}

__device__ __forceinline__ int refl(int i) {
    if (i < 0) i = -i;
    if (i >= GHH) i = 2 * GHH - 2 - i;
    return i;
}

__device__ __forceinline__ float gelu_fast(float v) {
    float u = 0.7978845608f * v * (1.f + 0.044715f * v * v);
    float e = __expf(2.f * u);
    float th = 1.f - 2.f / (e + 1.f);
    return 0.5f * v * (1.f + th);
}

// ---------------- linear ----------------
__global__ void linear_kernel(const float* __restrict__ x,
                              const float* __restrict__ W,
                              const float* __restrict__ bias,
                              float* __restrict__ f0) {
    int gwave = (blockIdx.x * blockDim.x + threadIdx.x) >> 6;
    int lane = threadIdx.x & 63;
    if (gwave >= BATCH * 972) return;
    int b = gwave / 972, j = gwave % 972;
    const float* xr = x + b * 1000;
    const float* wr = W + j * 1000;
    float s = 0.f;
    for (int k = lane; k < 1000; k += 64)
        s += xr[k] * wr[k];
    #pragma unroll
    for (int off = 32; off; off >>= 1) s += __shfl_down(s, off, 64);
    if (lane == 0) f0[gwave] = s + bias[j];
}

// ---------------- bicubic 18 -> 224 ----------------
__device__ __forceinline__ float cubicw(float d) {
    d = fabsf(d);
    if (d <= 1.f) return ((1.25f * d - 2.25f) * d) * d + 1.f;
    if (d < 2.f)  return ((-0.75f * d + 3.75f) * d - 6.f) * d + 3.f;
    return 0.f;
}

__global__ void bicubic_kernel(const float* __restrict__ f0, float* __restrict__ hr) {
    int idx = blockIdx.x * blockDim.x + threadIdx.x;
    if (idx >= BATCH * 3 * HW) return;
    int w = idx % GWW;
    int h = (idx / GWW) % GHH;
    int bc = idx / HW;
    const float* src = f0 + bc * 18 * 18;
    float xx = (w + 0.5f) * (18.f / 224.f) - 0.5f;
    float yy = (h + 0.5f) * (18.f / 224.f) - 0.5f;
    float fx0 = floorf(xx), fy0 = floorf(yy);
    int x0 = (int)fx0, y0 = (int)fy0;
    float tx = xx - fx0, ty = yy - fy0;
    float wx[4], wy[4];
    int ix[4], iy[4];
    #pragma unroll
    for (int k = 0; k < 4; k++) {
        wx[k] = cubicw(tx - (float)(k - 1));
        wy[k] = cubicw(ty - (float)(k - 1));
        int a = x0 + (k - 1); ix[k] = min(max(a, 0), 17);
        a = y0 + (k - 1);     iy[k] = min(max(a, 0), 17);
    }
    float acc = 0.f;
    #pragma unroll
    for (int ky = 0; ky < 4; ky++) {
        float rowv = 0.f;
        #pragma unroll
        for (int kx = 0; kx < 4; kx++) rowv += wx[kx] * src[iy[ky] * 18 + ix[kx]];
        acc += wy[ky] * rowv;
    }
    hr[idx] = acc;
}

// ---------------- range_proj via MFMA: layer1 VALU, layer2 = mfma_f32_16x16x32_f16 ----------------
// LDS A-region: chunk-planar h1 f16 [4 planes][256 px][8 halves]  (16 KB)
// LDS D-region: pixel-major f16 [256 px][32 halves], 80 B/px padded stride (20 KB)
__global__ __launch_bounds__(256) void rangeproj_kernel(
    const float* __restrict__ guid,
    const float* __restrict__ w1, const float* __restrict__ b1,
    const float* __restrict__ w2, const float* __restrict__ b2,
    float4* __restrict__ q4) {
    __shared__ __align__(16) char sh1b[4 * 256 * 16];   // 16384 B
    __shared__ __align__(16) char sDb[256 * 80];        // 20480 B
    const int tid = threadIdx.x;
    const int idx = blockIdx.x * 256 + tid;
    const int b = idx / HW, pix = idx % HW;
    float g0 = guid[(b * 3 + 0) * HW + pix];
    float g1 = guid[(b * 3 + 1) * HW + pix];
    float g2 = guid[(b * 3 + 2) * HW + pix];

    // layer 1 (weights uniform -> s_loads)
    float h1[QC];
    #pragma unroll
    for (int k = 0; k < QC; k++) {
        float v = w1[k * 3] * g0 + w1[k * 3 + 1] * g1 + w1[k * 3 + 2] * g2 + b1[k];
        h1[k] = gelu_fast(v);
    }
    // pack to f16, store chunk-planar (plane k: 256 px x 16B, contiguous per wave -> conflict-free)
    #pragma unroll
    for (int k = 0; k < 4; k++) {
        union { _Float16 h[8]; float4 f4; } u;
        #pragma unroll
        for (int j = 0; j < 8; j++) u.h[j] = (_Float16)h1[k * 8 + j];
        *(float4*)(sh1b + k * 4096 + tid * 16) = u.f4;
    }
    __syncthreads();

    const int l = tid & 63, w = tid >> 6;
    const int n0 = l & 15;          // out-channel (C/D col) / A-row m
    const int kq = l >> 4;          // k-chunk quad
    const int wbase = w * 64;

    // B fragments from w2 (f32 global -> f16), B[n][k] row-major == w2 layout
    v8h B0, B1;
    #pragma unroll
    for (int j = 0; j < 8; j++) {
        B0[j] = (_Float16)w2[n0 * QC + kq * 8 + j];
        B1[j] = (_Float16)w2[(n0 + 16) * QC + kq * 8 + j];
    }
    const float bias0 = b2[n0], bias1 = b2[n0 + 16];

    #pragma unroll
    for (int t = 0; t < 4; t++) {
        // A-frag: pixel m = wbase+16t+n0, k-chunk kq
        v8h A = *(const v8h*)(sh1b + kq * 4096 + (wbase + 16 * t + n0) * 16);
        v4f D0 = {0.f, 0.f, 0.f, 0.f}, D1 = {0.f, 0.f, 0.f, 0.f};
        D0 = __builtin_amdgcn_mfma_f32_16x16x32_f16(A, B0, D0, 0, 0, 0);
        D1 = __builtin_amdgcn_mfma_f32_16x16x32_f16(A, B1, D1, 0, 0, 0);
        // C/D: col(lane&15)=out-ch, row(quad*4+reg)=pixel  [m89-verified mapping]
        #pragma unroll
        for (int r = 0; r < 4; r++) {
            int p = wbase + 16 * t + 4 * kq + r;
            _Float16* dst = (_Float16*)(sDb + p * 80);
            dst[n0]      = (_Float16)(D0[r] + bias0);
            dst[n0 + 16] = (_Float16)(D1[r] + bias1);
        }
    }
    __syncthreads();

    // coalesced global store: q4 element t2 = [pixel t2>>2][chunk t2&3]
    size_t gbase = (size_t)blockIdx.x * 1024;
    #pragma unroll
    for (int k2 = 0; k2 < 4; k2++) {
        int t2 = k2 * 256 + tid;
        float4 v = *(const float4*)(sDb + (t2 >> 2) * 80 + (t2 & 3) * 16);
        q4[gbase + t2] = v;
    }
}

// ---------------- fused JBU (exact R5 structure: 16x16 tile, 1 px/thread, 47.8 us) ----------------
__global__ __launch_bounds__(256, 4) void jbu_kernel(
    const float4* __restrict__ q4,
    const float* __restrict__ hr,
    float* __restrict__ outF,
    const float* __restrict__ temps,
    const float* __restrict__ sigmas,
    int stage)
{
    __shared__ __align__(16) float4 sq[4 * CS];   // 31040 B, q tile chunk-planar
    __shared__ __align__(16) float4 sh[TPIX];     //  7744 B, hr tile (3ch + pad)
    int tx = threadIdx.x, ty = threadIdx.y;
    int tid = ty * TILE + tx;
    int b = blockIdx.z;
    int h0 = blockIdx.y * TILE, w0 = blockIdx.x * TILE;

    bool interior = (h0 >= RAD) && (h0 + TILE + RAD <= GHH) &&
                    (w0 >= RAD) && (w0 + TILE + RAD <= GWW);

    if (interior) {
        const float4* qb = q4 + ((size_t)(b * HW + (h0 - RAD) * GWW + (w0 - RAD))) * 4;
        for (int i = tid; i < 4 * TPIX; i += 256) {
            int px = i >> 2, c = i & 3;
            int r = px / TP, cc = px % TP;
            sq[c * CS + px] = qb[((size_t)r * GWW + cc) * 4 + c];
        }
        const float* hb = hr + (size_t)b * 3 * HW + (size_t)(h0 - RAD) * GWW + (w0 - RAD);
        for (int i = tid; i < TPIX; i += 256) {
            int r = i / TP, cx = i % TP;
            size_t base = (size_t)r * GWW + cx;
            sh[i] = make_float4(hb[base], hb[base + HW], hb[base + 2 * HW], 0.f);
        }
    } else {
        for (int i = tid; i < 4 * TPIX; i += 256) {
            int px = i >> 2, c = i & 3;
            int r = px / TP, cc = px % TP;
            int gh = refl(h0 - RAD + r);
            int gw = refl(w0 - RAD + cc);
            sq[c * CS + px] = q4[(size_t)(b * HW + gh * GWW + gw) * 4 + c];
        }
        for (int i = tid; i < TPIX; i += 256) {
            int r = i / TP, cx = i % TP;
            int gh = refl(h0 - RAD + r);
            int gw = refl(w0 - RAD + cx);
            size_t base = (size_t)b * 3 * HW + (size_t)gh * GWW + gw;
            sh[i] = make_float4(hr[base], hr[base + HW], hr[base + 2 * HW], 0.f);
        }
    }
    __syncthreads();

    int ci = (ty + RAD) * TP + tx + RAD;
    float4 c0 = sq[ci], c1 = sq[CS + ci], c2 = sq[2 * CS + ci], c3 = sq[3 * CS + ci];

    float s[NPTS];
    int p = 0;
    #pragma unroll
    for (int di = 0; di < DIAM; di++) {
        int rb = (ty + di) * TP + tx;
        #pragma unroll
        for (int dj = 0; dj < DIAM; dj++, p++) {
            int ni = rb + dj;
            float acc = dot16(c0, sq[ni], 0.f);
            acc = dot16(c1, sq[CS + ni], acc);
            acc = dot16(c2, sq[2 * CS + ni], acc);
            acc = dot16(c3, sq[3 * CS + ni], acc);
            s[p] = acc;
        }
    }

    // ---- softmax * spatial, renormalize ----
    float t = __expf(temps[stage]);
    t = fminf(fmaxf(t, 1e-4f), 1e4f);
    float sig = sigmas[stage];
    float inv2s2 = 1.f / (2.f * sig * sig);
    float m = -1e30f;
    #pragma unroll
    for (int p2 = 0; p2 < NPTS; p2++) { s[p2] *= t; m = fmaxf(m, s[p2]); }
    float den = 0.f;
    #pragma unroll
    for (int p2 = 0; p2 < NPTS; p2++) { s[p2] = __expf(s[p2] - m); den += s[p2]; }
    float rden = 1.f / den;
    float ksum = 0.f;
    #pragma unroll
    for (int p2 = 0; p2 < NPTS; p2++) {
        int di = p2 / 7, dj = p2 % 7;
        float dy = (float)(di - 3) * (1.f / 3.f);
        float dx = (float)(dj - 3) * (1.f / 3.f);
        float spat = __expf(-(dy * dy + dx * dx) * inv2s2);
        s[p2] = s[p2] * rden * spat;
        ksum += s[p2];
    }
    float rk = 1.f / fmaxf(ksum, 1e-7f);

    // ---- adaptive conv from sh ----
    float o0 = 0.f, o1 = 0.f, o2 = 0.f;
    p = 0;
    #pragma unroll
    for (int di = 0; di < DIAM; di++) {
        int rb = (ty + di) * TP + tx;
        #pragma unroll
        for (int dj = 0; dj < DIAM; dj++, p++) {
            float4 hv = sh[rb + dj];
            float kp = s[p] * rk;
            o0 += kp * hv.x;
            o1 += kp * hv.y;
            o2 += kp * hv.z;
        }
    }
    size_t obase = (size_t)b * 3 * HW + (size_t)(h0 + ty) * GWW + (w0 + tx);
    outF[obase]          = o0;
    outF[obase + HW]     = o1;
    outF[obase + 2 * HW] = o2;
}

extern "C" void kernel_launch(void* const* d_in, const int* in_sizes, int n_in,
                              void* d_out, int out_size, void* d_ws, size_t ws_size,
                              hipStream_t stream) {
    const float* x      = (const float*)d_in[0];
    const float* guid   = (const float*)d_in[1];
    const float* lw     = (const float*)d_in[2];
    const float* lb     = (const float*)d_in[3];
    const float* w1s    = (const float*)d_in[4];
    const float* b1s    = (const float*)d_in[5];
    const float* w2s    = (const float*)d_in[6];
    const float* b2s    = (const float*)d_in[7];
    const float* temps  = (const float*)d_in[8];
    const float* sigmas = (const float*)d_in[9];

    char* ws = (char*)d_ws;
    const size_t Q_BYTES  = (size_t)BATCH * HW * QC * sizeof(__half);  // 25,690,112
    const size_t F_BYTES  = (size_t)BATCH * 3 * HW * sizeof(float);    //  4,816,896
    float4* q4 = (float4*)ws;
    float* hrA = (float*)(ws + Q_BYTES);
    float* hrB = (float*)(ws + Q_BYTES + F_BYTES);
    float* f0  = (float*)(ws + Q_BYTES + 2 * F_BYTES);

    linear_kernel<<<1944, 256, 0, stream>>>(x, lw, lb, f0);
    bicubic_kernel<<<(BATCH * 3 * HW + 255) / 256, 256, 0, stream>>>(f0, hrA);

    dim3 jgrid(14, 14, BATCH), jblock(16, 16);
    const float* hins[4]  = { hrA, hrB, hrA, hrB };
    float*       fouts[4] = { hrB, hrA, hrB, (float*)d_out };
    for (int s = 0; s < 4; s++) {
        rangeproj_kernel<<<(BATCH * HW) / 256, 256, 0, stream>>>(
            guid, w1s + s * 96, b1s + s * 32, w2s + s * 1024, b2s + s * 32, q4);
        jbu_kernel<<<jgrid, jblock, 0, stream>>>(
            q4, hins[s], fouts[s], temps, sigmas, s);
    }
}